// Round 5
// baseline (398.250 us; speedup 1.0000x reference)
//
#include <hip/hip_runtime.h>
#include <cstdint>
#include <cstddef>

#define MROWS 24000
#define NCOLS 1024
#define KDIM  768
#define MT 188          // ceil(24000/128) m-tiles (padded to 24064 rows)
#define KT 48           // 768/16 k-tiles
#define NT 4            // 1024/256 n-tiles

typedef _Float16 f16x8  __attribute__((ext_vector_type(8)));
typedef float    f32x16 __attribute__((ext_vector_type(16)));

typedef __attribute__((address_space(1))) void as1_void;
typedef __attribute__((address_space(3))) void as3_void;

// ---- workspace layout (bytes) ----
#define A_BYTES   (188ull*48*8192)            // 73,924,608
#define B_OFF     A_BYTES
#define B_BYTES   (4ull*48*16384)             // 3,145,728
#define CH_OFF    (A_BYTES + B_BYTES)         // 77,070,336
#define PART_OFF  (CH_OFF + 4096)             // 77,074,432
#define WS_NEED   (PART_OFF + 24064ull*4*8)   // 77,844,480

// ---------------- conv A: embed -> tiled fp16 hi/lo ----------------
__global__ void k_tile_A(const float* __restrict__ E, _Float16* __restrict__ Aw) {
  int bid = blockIdx.x;            // mt*48 + kt
  int mt = bid / 48, kt = bid % 48;
  int t = threadIdx.x;             // 256
  int r = t >> 1, p = t & 1;
  int row = mt * 128 + r;
  __shared__ _Float16 lh[2][128][8];
  __shared__ _Float16 ll[2][128][8];
  float x[8];
  if (row < MROWS) {
    const float4* s4 = (const float4*)(E + (size_t)row * KDIM + kt * 16 + p * 8);
    float4 v0 = s4[0], v1 = s4[1];
    x[0]=v0.x; x[1]=v0.y; x[2]=v0.z; x[3]=v0.w; x[4]=v1.x; x[5]=v1.y; x[6]=v1.z; x[7]=v1.w;
  } else {
#pragma unroll
    for (int e = 0; e < 8; ++e) x[e] = 0.f;
  }
#pragma unroll
  for (int e = 0; e < 8; ++e) {
    _Float16 h = (_Float16)x[e];
    lh[p][r][e] = h;
    ll[p][r][e] = (_Float16)(x[e] - (float)h);
  }
  __syncthreads();
  const uint4* sh = (const uint4*)&lh[0][0][0];
  const uint4* sl = (const uint4*)&ll[0][0][0];
  uint4* dst = (uint4*)(Aw + (size_t)bid * 4096);   // 8192 B per tile
  dst[t]       = sh[t];    // h region: 256 chunks
  dst[256 + t] = sl[t];    // l region
}

// ---------------- conv B: centers -> tiled fp16 hi/lo ----------------
__global__ void k_tile_B(const float* __restrict__ C, _Float16* __restrict__ Bw) {
  int bid = blockIdx.x;            // nt*48 + kt
  int nt = bid / 48, kt = bid % 48;
  int t = threadIdx.x;             // 512
  int c = t >> 1, p = t & 1;
  __shared__ _Float16 lh[2][256][8];
  __shared__ _Float16 ll[2][256][8];
  const float4* s4 = (const float4*)(C + (size_t)(nt * 256 + c) * KDIM + kt * 16 + p * 8);
  float4 v0 = s4[0], v1 = s4[1];
  float x[8] = {v0.x, v0.y, v0.z, v0.w, v1.x, v1.y, v1.z, v1.w};
#pragma unroll
  for (int e = 0; e < 8; ++e) {
    _Float16 h = (_Float16)x[e];
    lh[p][c][e] = h;
    ll[p][c][e] = (_Float16)(x[e] - (float)h);
  }
  __syncthreads();
  const uint4* sh = (const uint4*)&lh[0][0][0];
  const uint4* sl = (const uint4*)&ll[0][0][0];
  uint4* dst = (uint4*)(Bw + (size_t)bid * 8192);   // 16384 B per tile
  dst[t]       = sh[t];    // h region: 512 chunks
  dst[512 + t] = sl[t];    // l region
}

// ---------------- 0.5*||c||^2 ----------------
__global__ void k_chalf(const float* __restrict__ C, float* __restrict__ ch) {
  int c = blockIdx.x, t = threadIdx.x;   // 256
  const float* src = C + (size_t)c * KDIM;
  float sq = 0.f;
#pragma unroll
  for (int i = 0; i < 3; ++i) {
    float x = src[t + i * 256];
    sq = fmaf(x, x, sq);
  }
#pragma unroll
  for (int m = 1; m < 64; m <<= 1) sq += __shfl_xor(sq, m, 64);
  __shared__ float part[4];
  if ((t & 63) == 0) part[t >> 6] = sq;
  __syncthreads();
  if (t == 0) ch[c] = 0.5f * ((part[0] + part[1]) + (part[2] + part[3]));
}

#define MFMA16(a, b, c) __builtin_amdgcn_mfma_f32_32x32x16_f16((a), (b), (c), 0, 0, 0)

// ---------------- fused GEMM: 3-deep per-wave register pipeline ----------------
// Block tile 128x256, 8 waves (2x4), wave tile 64x64, acc[2][2] 32x32 frags.
// No LDS, no barriers, no inline asm in the K-loop. Each wave runs a private
// 3-deep software pipeline over three NAMED register fragment sets (32 VGPR
// each): set for ktile j is loaded ~3 iterations (>=1200 cyc) before its MFMAs
// consume it, so even HBM-miss latency is covered per-wave (prior rounds all
// issued ktile j's loads at most one rendezvous ahead -> ~1100 cyc exposed
// stall per ktile, MfmaUtil pinned at ~26%). The compiler's dependency-driven
// s_waitcnt emits vmcnt(16) before each MFMA cluster (two newer sets in
// flight). A single non-stalling wave can saturate its SIMD matrix pipe;
// 2 waves/SIMD (64 acc + 96 frag + misc regs ~ 176 unified) give slack.
__global__ __launch_bounds__(512, 2) void k_gemm(
    const _Float16* __restrict__ Aw, const _Float16* __restrict__ Bw,
    const float* __restrict__ ch, uint2* __restrict__ part) {
  __shared__ float red_v[4][128];
  __shared__ int   red_i[4][128];

  const int bid0 = blockIdx.x;                  // 0..751
  const int swz = (bid0 & 7) * 94 + (bid0 >> 3);  // 752 = 8*94, bijective XCD swizzle
  const int nt = swz / MT, mt = swz % MT;

  const int tid = threadIdx.x, lane = tid & 63, wid = tid >> 6;  // 8 waves
  const int wm = wid >> 2, wn = wid & 3;        // 2x4 wave grid, wave tile 64x64
  const int lo5 = lane & 31, p = lane >> 5;

  const char* Ab = (const char*)Aw + (size_t)mt * (48 * 8192);
  const char* Bb = (const char*)Bw + (size_t)nt * (48 * 16384);

  const int offA = p * 2048 + (wm * 64 + lo5) * 16;   // + mi*512; lo plane +4096
  const int offB = p * 4096 + (wn * 64 + lo5) * 16;   // + ni*512; lo plane +8192

  f32x16 acc[2][2] = {};

  // three named fragment sets (ring), all indices compile-time static
  f16x8 ah0_0, ah1_0, al0_0, al1_0, bh0_0, bh1_0, bl0_0, bl1_0;
  f16x8 ah0_1, ah1_1, al0_1, al1_1, bh0_1, bh1_1, bl0_1, bl1_1;
  f16x8 ah0_2, ah1_2, al0_2, al1_2, bh0_2, bh1_2, bl0_2, bl1_2;

#define LOADSET(S, kt)                                                        \
  do {                                                                        \
    const char* ga_ = Ab + (kt) * 8192;                                       \
    const char* gb_ = Bb + (kt) * 16384;                                      \
    ah0_##S = *(const f16x8*)(ga_ + offA);                                    \
    ah1_##S = *(const f16x8*)(ga_ + offA + 512);                              \
    al0_##S = *(const f16x8*)(ga_ + 4096 + offA);                             \
    al1_##S = *(const f16x8*)(ga_ + 4096 + offA + 512);                       \
    bh0_##S = *(const f16x8*)(gb_ + offB);                                    \
    bh1_##S = *(const f16x8*)(gb_ + offB + 512);                              \
    bl0_##S = *(const f16x8*)(gb_ + 8192 + offB);                             \
    bl1_##S = *(const f16x8*)(gb_ + 8192 + offB + 512);                       \
  } while (0)

  // per-acc chain order (hh, h*bl, al*bh), kt ascending: bitwise-identical
  // accumulation to all previously verified versions
#define MFMASET(S)                                                            \
  do {                                                                        \
    __builtin_amdgcn_s_setprio(1);                                            \
    acc[0][0] = MFMA16(ah0_##S, bh0_##S, acc[0][0]);                          \
    acc[0][0] = MFMA16(ah0_##S, bl0_##S, acc[0][0]);                          \
    acc[0][0] = MFMA16(al0_##S, bh0_##S, acc[0][0]);                          \
    acc[1][0] = MFMA16(ah1_##S, bh0_##S, acc[1][0]);                          \
    acc[1][0] = MFMA16(ah1_##S, bl0_##S, acc[1][0]);                          \
    acc[1][0] = MFMA16(al1_##S, bh0_##S, acc[1][0]);                          \
    acc[0][1] = MFMA16(ah0_##S, bh1_##S, acc[0][1]);                          \
    acc[0][1] = MFMA16(ah0_##S, bl1_##S, acc[0][1]);                          \
    acc[0][1] = MFMA16(al0_##S, bh1_##S, acc[0][1]);                          \
    acc[1][1] = MFMA16(ah1_##S, bh1_##S, acc[1][1]);                          \
    acc[1][1] = MFMA16(ah1_##S, bl1_##S, acc[1][1]);                          \
    acc[1][1] = MFMA16(al1_##S, bh1_##S, acc[1][1]);                          \
    __builtin_amdgcn_s_setprio(0);                                            \
  } while (0)

  // prologue: 3 ktiles in flight (24 loads)
  LOADSET(0, 0);
  LOADSET(1, 1);
  LOADSET(2, 2);

  // main: 15 ring turns cover ktiles 0..44, staging 3..47
#pragma unroll 1
  for (int j = 0; j < KT - 3; j += 3) {
    MFMASET(0); LOADSET(0, j + 3);
    MFMASET(1); LOADSET(1, j + 4);
    MFMASET(2); LOADSET(2, j + 5);
  }
  // tail: ktiles 45,46,47 (no staging)
  MFMASET(0);
  MFMASET(1);
  MFMASET(2);

#undef LOADSET
#undef MFMASET

  // ---- epilogue: per-row argmax over this wave's 64 cols, then merge across wn ----
  int c0 = nt * 256 + wn * 64 + lo5;
  int c1 = c0 + 32;
  float ch0 = ch[c0];
  float ch1 = ch[c1];
#pragma unroll
  for (int mi = 0; mi < 2; ++mi)
#pragma unroll
    for (int q = 0; q < 16; ++q) {
      float s0 = acc[mi][0][q] - ch0;
      float s1 = acc[mi][1][q] - ch1;
      float v = s0; int ix = c0;
      if (s1 > v) { v = s1; ix = c1; }   // c1 > c0: strict > keeps first index on ties
#pragma unroll
      for (int m = 1; m <= 16; m <<= 1) {
        float ov = __shfl_xor(v, m, 64);
        int   oi = __shfl_xor(ix, m, 64);
        if (ov > v || (ov == v && oi < ix)) { v = ov; ix = oi; }
      }
      if (lo5 == 0) {
        int rr = (q & 3) + ((q >> 2) << 3) + (p << 2);   // C/D row within 32x32 tile
        int rloc = wm * 64 + mi * 32 + rr;               // 0..127, unique per (wm,mi,q,p)
        red_v[wn][rloc] = v;
        red_i[wn][rloc] = ix;
      }
    }
  __syncthreads();
  if (tid < 128) {
    float v = red_v[0][tid];
    int ix = red_i[0][tid];
#pragma unroll
    for (int w = 1; w < 4; ++w) {       // wn ascending => col ascending; strict > keeps first
      float ov = red_v[w][tid];
      int oi = red_i[w][tid];
      if (ov > v) { v = ov; ix = oi; }
    }
    int rowg = mt * 128 + tid;
    part[rowg * 4 + nt] = uint2{ __float_as_uint(v), (unsigned)ix };
  }
}

// ---------------- merge the 4 per-ntile candidates ----------------
__global__ void k_merge(const uint2* __restrict__ part, int* __restrict__ out) {
  int r = blockIdx.x * 256 + threadIdx.x;
  if (r >= MROWS) return;
  uint2 b0 = part[r * 4];
  float bvv = __uint_as_float(b0.x);
  int bii = (int)b0.y;
#pragma unroll
  for (int j = 1; j < 4; ++j) {
    uint2 pj = part[r * 4 + j];
    float v = __uint_as_float(pj.x);
    if (v > bvv) { bvv = v; bii = (int)pj.y; }   // nt ascending => idx ascending; strict >
  }
  out[r] = bii;
}

// ---------------- fallback (ws too small): fp32 wave-per-row ----------------
__global__ void k_naive(const float* __restrict__ E, const float* __restrict__ C,
                        int* __restrict__ out) {
  int row = blockIdx.x * 4 + (threadIdx.x >> 6);
  int lane = threadIdx.x & 63;
  const float* e = E + (size_t)row * KDIM;
  float bvv = -3.4e38f;
  int bii = 0;
  for (int c = 0; c < NCOLS; ++c) {
    const float* cc = C + (size_t)c * KDIM;
    float dot = 0.f, csq = 0.f;
    for (int d = lane; d < KDIM; d += 64) {
      float cv = cc[d];
      dot = fmaf(e[d], cv, dot);
      csq = fmaf(cv, cv, csq);
    }
#pragma unroll
    for (int m = 1; m < 64; m <<= 1) {
      dot += __shfl_xor(dot, m, 64);
      csq += __shfl_xor(csq, m, 64);
    }
    float s = dot - 0.5f * csq;
    if (s > bvv) { bvv = s; bii = c; }
  }
  if (lane == 0) out[row] = bii;
}

extern "C" void kernel_launch(void* const* d_in, const int* in_sizes, int n_in,
                              void* d_out, int out_size, void* d_ws, size_t ws_size,
                              hipStream_t stream) {
  const float* embed   = (const float*)d_in[0];
  const float* centers = (const float*)d_in[1];
  int* out = (int*)d_out;

  if (ws_size >= WS_NEED) {
    char* w = (char*)d_ws;
    _Float16* Aw = (_Float16*)w;
    _Float16* Bw = (_Float16*)(w + B_OFF);
    float*    ch = (float*)(w + CH_OFF);
    uint2*  partb = (uint2*)(w + PART_OFF);
    k_tile_A<<<188 * 48, 256, 0, stream>>>(embed, Aw);
    k_tile_B<<<4 * 48, 512, 0, stream>>>(centers, Bw);
    k_chalf<<<1024, 256, 0, stream>>>(centers, ch);
    k_gemm<<<752, 512, 0, stream>>>(Aw, Bw, ch, partb);
    k_merge<<<94, 256, 0, stream>>>(partb, out);
  } else {
    k_naive<<<6000, 256, 0, stream>>>(embed, centers, out);
  }
}

// Round 6
// 198.223 us; speedup vs baseline: 2.0091x; 2.0091x over previous
//
#include <hip/hip_runtime.h>
#include <cstdint>
#include <cstddef>

#define MROWS 24000
#define NCOLS 1024
#define KDIM  768
#define MT 188          // ceil(24000/128) m-tiles (padded to 24064 rows)
#define KT 48           // 768/16 k-tiles
#define NT 2            // 1024/512 n-tiles (gemm); workspace B still tiled in 256-col units

typedef _Float16 f16x8  __attribute__((ext_vector_type(8)));
typedef float    f32x16 __attribute__((ext_vector_type(16)));

typedef __attribute__((address_space(1))) void as1_void;
typedef __attribute__((address_space(3))) void as3_void;

// ---- workspace layout (bytes) ----
#define A_BYTES   (188ull*48*8192)            // 73,924,608
#define B_OFF     A_BYTES
#define B_BYTES   (4ull*48*16384)             // 3,145,728
#define CH_OFF    (A_BYTES + B_BYTES)         // 77,070,336
#define PART_OFF  (CH_OFF + 4096)             // 77,074,432
#define WS_NEED   (PART_OFF + 24064ull*4*8)   // 77,844,480

// ---------------- conv A: embed -> tiled fp16 hi/lo ----------------
__global__ void k_tile_A(const float* __restrict__ E, _Float16* __restrict__ Aw) {
  int bid = blockIdx.x;            // mt*48 + kt
  int mt = bid / 48, kt = bid % 48;
  int t = threadIdx.x;             // 256
  int r = t >> 1, p = t & 1;
  int row = mt * 128 + r;
  __shared__ _Float16 lh[2][128][8];
  __shared__ _Float16 ll[2][128][8];
  float x[8];
  if (row < MROWS) {
    const float4* s4 = (const float4*)(E + (size_t)row * KDIM + kt * 16 + p * 8);
    float4 v0 = s4[0], v1 = s4[1];
    x[0]=v0.x; x[1]=v0.y; x[2]=v0.z; x[3]=v0.w; x[4]=v1.x; x[5]=v1.y; x[6]=v1.z; x[7]=v1.w;
  } else {
#pragma unroll
    for (int e = 0; e < 8; ++e) x[e] = 0.f;
  }
#pragma unroll
  for (int e = 0; e < 8; ++e) {
    _Float16 h = (_Float16)x[e];
    lh[p][r][e] = h;
    ll[p][r][e] = (_Float16)(x[e] - (float)h);
  }
  __syncthreads();
  const uint4* sh = (const uint4*)&lh[0][0][0];
  const uint4* sl = (const uint4*)&ll[0][0][0];
  uint4* dst = (uint4*)(Aw + (size_t)bid * 4096);   // 8192 B per tile
  dst[t]       = sh[t];    // h region: 256 chunks
  dst[256 + t] = sl[t];    // l region
}

// ---------------- conv B: centers -> tiled fp16 hi/lo ----------------
__global__ void k_tile_B(const float* __restrict__ C, _Float16* __restrict__ Bw) {
  int bid = blockIdx.x;            // nt*48 + kt   (nt in 256-col units, 0..3)
  int nt = bid / 48, kt = bid % 48;
  int t = threadIdx.x;             // 512
  int c = t >> 1, p = t & 1;
  __shared__ _Float16 lh[2][256][8];
  __shared__ _Float16 ll[2][256][8];
  const float4* s4 = (const float4*)(C + (size_t)(nt * 256 + c) * KDIM + kt * 16 + p * 8);
  float4 v0 = s4[0], v1 = s4[1];
  float x[8] = {v0.x, v0.y, v0.z, v0.w, v1.x, v1.y, v1.z, v1.w};
#pragma unroll
  for (int e = 0; e < 8; ++e) {
    _Float16 h = (_Float16)x[e];
    lh[p][c][e] = h;
    ll[p][c][e] = (_Float16)(x[e] - (float)h);
  }
  __syncthreads();
  const uint4* sh = (const uint4*)&lh[0][0][0];
  const uint4* sl = (const uint4*)&ll[0][0][0];
  uint4* dst = (uint4*)(Bw + (size_t)bid * 8192);   // 16384 B per tile
  dst[t]       = sh[t];    // h region: 512 chunks
  dst[512 + t] = sl[t];    // l region
}

// ---------------- 0.5*||c||^2 ----------------
__global__ void k_chalf(const float* __restrict__ C, float* __restrict__ ch) {
  int c = blockIdx.x, t = threadIdx.x;   // 256
  const float* src = C + (size_t)c * KDIM;
  float sq = 0.f;
#pragma unroll
  for (int i = 0; i < 3; ++i) {
    float x = src[t + i * 256];
    sq = fmaf(x, x, sq);
  }
#pragma unroll
  for (int m = 1; m < 64; m <<= 1) sq += __shfl_xor(sq, m, 64);
  __shared__ float part[4];
  if ((t & 63) == 0) part[t >> 6] = sq;
  __syncthreads();
  if (t == 0) ch[c] = 0.5f * ((part[0] + part[1]) + (part[2] + part[3]));
}

#define MFMA16(a, b, c) __builtin_amdgcn_mfma_f32_32x32x16_f16((a), (b), (c), 0, 0, 0)

// ---------------- fused GEMM: 128x512 block tile, 16 waves, ring-3 counted vmcnt ----
// Block tile 128x512 (NT=2): each A panel now read by 2 blocks instead of 4 ->
// the A L2-miss stream per unit of MFMA work halves (A is the L2-cold operand:
// same-XCD blocks all have distinct mt, so A ALWAYS misses L2; B is a hot
// 1.5MB/XCD panel). 16 waves (2x8), wave tile 64x64, acc[2][2] -- identical
// per-wave code and per-acc MFMA chain order as the verified kernel ->
// bitwise-identical scores. Ring-3 LDS sets of 40KB {A 8K | B-lo256 16K |
// B-hi256 16K} = 120KB + 8KB reduce = 128KB -> 1 block/CU = 4 waves/SIMD.
// Stage = 3 DMA insts/ktile for every wave (A dup-written by both half-blocks:
// benign identical-byte DMA, keeps per-wave vmcnt uniform). Entry wait
// vmcnt(3): tile j landed, tile j+1's 3 stay in flight (R2 skeleton).
__global__ __launch_bounds__(1024, 4) void k_gemm(
    const _Float16* __restrict__ Aw, const _Float16* __restrict__ Bw,
    const float* __restrict__ ch, uint2* __restrict__ part) {
  __shared__ __align__(16) char smem[3][40960];
  __shared__ float red_v[8][128];
  __shared__ int   red_i[8][128];

  const int bid0 = blockIdx.x;                    // 0..375
  const int swz = (bid0 & 7) * 47 + (bid0 >> 3);  // 376 = 8*47, bijective XCD swizzle
  const int nt = swz / MT, mt = swz % MT;         // nt in 512-col units (0..1)

  const int tid = threadIdx.x, lane = tid & 63, wid = tid >> 6;  // 16 waves
  const int wm = wid >> 3, wn = wid & 7;          // 2x8 wave grid, wave tile 64x64
  const int lo5 = lane & 31, p = lane >> 5;

  const char* Ab  = (const char*)Aw + (size_t)mt * (48 * 8192);
  const char* Bb0 = (const char*)Bw + (size_t)(nt * 2 + 0) * (48 * 16384);
  const char* Bb1 = (const char*)Bw + (size_t)(nt * 2 + 1) * (48 * 16384);

  auto stage = [&](char* sb, int kt) {   // 3 insts: A 8KB (dup), B 2x16KB
    __builtin_amdgcn_global_load_lds((as1_void*)(Ab + kt * 8192 + (tid & 511) * 16),
                                     (as3_void*)(sb + (tid & 511) * 16), 16, 0, 0);
    __builtin_amdgcn_global_load_lds((as1_void*)(Bb0 + (size_t)kt * 16384 + tid * 16),
                                     (as3_void*)(sb + 8192 + tid * 16), 16, 0, 0);
    __builtin_amdgcn_global_load_lds((as1_void*)(Bb1 + (size_t)kt * 16384 + tid * 16),
                                     (as3_void*)(sb + 24576 + tid * 16), 16, 0, 0);
  };

  f32x16 acc[2][2] = {};
  // A set: [hi 4K: [2p][128r][16B]][lo 4K]; B set: two 16K old-tiles, each
  // [hi 8K: [2p][256c][16B]][lo 8K]
  const int offA = p * 2048 + (wm * 64 + lo5) * 16;                        // +mi*512; lo +4096
  const int offB = 8192 + (wn >> 2) * 16384 + p * 4096
                 + ((wn & 3) * 64 + lo5) * 16;                             // +ni*512; lo +8192

  stage(smem[0], 0);
  stage(smem[1], 1);

  auto ktile = [&](const char* rb, char* wb, int j) {
    if (j < KT - 1) asm volatile("s_waitcnt vmcnt(3)" ::: "memory");
    else            asm volatile("s_waitcnt vmcnt(0)" ::: "memory");
    __builtin_amdgcn_s_barrier();
    f16x8 ah0 = *(const f16x8*)(rb + offA);
    f16x8 ah1 = *(const f16x8*)(rb + offA + 512);
    f16x8 al0 = *(const f16x8*)(rb + 4096 + offA);
    f16x8 al1 = *(const f16x8*)(rb + 4096 + offA + 512);
    f16x8 bh0 = *(const f16x8*)(rb + offB);
    f16x8 bh1 = *(const f16x8*)(rb + offB + 512);
    f16x8 bl0 = *(const f16x8*)(rb + 8192 + offB);
    f16x8 bl1 = *(const f16x8*)(rb + 8192 + offB + 512);
    if (j + 2 < KT) stage(wb, j + 2);   // wb freed by this entry barrier
    __builtin_amdgcn_s_setprio(1);
    // per-acc chain order (hh, h*bl, al*bh), kt ascending: bitwise-identical
    acc[0][0] = MFMA16(ah0, bh0, acc[0][0]);
    acc[0][0] = MFMA16(ah0, bl0, acc[0][0]);
    acc[0][0] = MFMA16(al0, bh0, acc[0][0]);
    acc[1][0] = MFMA16(ah1, bh0, acc[1][0]);
    acc[1][0] = MFMA16(ah1, bl0, acc[1][0]);
    acc[1][0] = MFMA16(al1, bh0, acc[1][0]);
    acc[0][1] = MFMA16(ah0, bh1, acc[0][1]);
    acc[0][1] = MFMA16(ah0, bl1, acc[0][1]);
    acc[0][1] = MFMA16(al0, bh1, acc[0][1]);
    acc[1][1] = MFMA16(ah1, bh1, acc[1][1]);
    acc[1][1] = MFMA16(ah1, bl1, acc[1][1]);
    acc[1][1] = MFMA16(al1, bh1, acc[1][1]);
    __builtin_amdgcn_s_setprio(0);
  };

  for (int j = 0; j < KT; j += 3) {      // KT = 48, divisible by 3
    ktile(smem[0], smem[2], j);
    ktile(smem[1], smem[0], j + 1);
    ktile(smem[2], smem[1], j + 2);
  }

  // ---- epilogue: per-row argmax over this wave's 64 cols, then merge across wn ----
  int c0 = nt * 512 + wn * 64 + lo5;
  int c1 = c0 + 32;
  float ch0 = ch[c0];
  float ch1 = ch[c1];
#pragma unroll
  for (int mi = 0; mi < 2; ++mi)
#pragma unroll
    for (int q = 0; q < 16; ++q) {
      float s0 = acc[mi][0][q] - ch0;
      float s1 = acc[mi][1][q] - ch1;
      float v = s0; int ix = c0;
      if (s1 > v) { v = s1; ix = c1; }   // c1 > c0: strict > keeps first index on ties
#pragma unroll
      for (int m = 1; m <= 16; m <<= 1) {
        float ov = __shfl_xor(v, m, 64);
        int   oi = __shfl_xor(ix, m, 64);
        if (ov > v || (ov == v && oi < ix)) { v = ov; ix = oi; }
      }
      if (lo5 == 0) {
        int rr = (q & 3) + ((q >> 2) << 3) + (p << 2);   // C/D row within 32x32 tile
        int rloc = wm * 64 + mi * 32 + rr;               // 0..127, unique per (wm,mi,q,p)
        red_v[wn][rloc] = v;
        red_i[wn][rloc] = ix;
      }
    }
  __syncthreads();
  if (tid < 128) {
    float v = red_v[0][tid];
    int ix = red_i[0][tid];
#pragma unroll
    for (int w = 1; w < 8; ++w) {       // wn ascending => col ascending; strict > keeps first
      float ov = red_v[w][tid];
      int oi = red_i[w][tid];
      if (ov > v) { v = ov; ix = oi; }
    }
    int rowg = mt * 128 + tid;
    part[rowg * 2 + nt] = uint2{ __float_as_uint(v), (unsigned)ix };
  }
}

// ---------------- merge the 2 per-ntile candidates ----------------
__global__ void k_merge(const uint2* __restrict__ part, int* __restrict__ out) {
  int r = blockIdx.x * 256 + threadIdx.x;
  if (r >= MROWS) return;
  uint2 b0 = part[r * 2];
  float bvv = __uint_as_float(b0.x);
  int bii = (int)b0.y;
  uint2 p1 = part[r * 2 + 1];
  float v1 = __uint_as_float(p1.x);
  if (v1 > bvv) { bvv = v1; bii = (int)p1.y; }   // nt ascending => idx ascending; strict >
  out[r] = bii;
}

// ---------------- fallback (ws too small): fp32 wave-per-row ----------------
__global__ void k_naive(const float* __restrict__ E, const float* __restrict__ C,
                        int* __restrict__ out) {
  int row = blockIdx.x * 4 + (threadIdx.x >> 6);
  int lane = threadIdx.x & 63;
  const float* e = E + (size_t)row * KDIM;
  float bvv = -3.4e38f;
  int bii = 0;
  for (int c = 0; c < NCOLS; ++c) {
    const float* cc = C + (size_t)c * KDIM;
    float dot = 0.f, csq = 0.f;
    for (int d = lane; d < KDIM; d += 64) {
      float cv = cc[d];
      dot = fmaf(e[d], cv, dot);
      csq = fmaf(cv, cv, csq);
    }
#pragma unroll
    for (int m = 1; m < 64; m <<= 1) {
      dot += __shfl_xor(dot, m, 64);
      csq += __shfl_xor(csq, m, 64);
    }
    float s = dot - 0.5f * csq;
    if (s > bvv) { bvv = s; bii = c; }
  }
  if (lane == 0) out[row] = bii;
}

extern "C" void kernel_launch(void* const* d_in, const int* in_sizes, int n_in,
                              void* d_out, int out_size, void* d_ws, size_t ws_size,
                              hipStream_t stream) {
  const float* embed   = (const float*)d_in[0];
  const float* centers = (const float*)d_in[1];
  int* out = (int*)d_out;

  if (ws_size >= WS_NEED) {
    char* w = (char*)d_ws;
    _Float16* Aw = (_Float16*)w;
    _Float16* Bw = (_Float16*)(w + B_OFF);
    float*    ch = (float*)(w + CH_OFF);
    uint2*  partb = (uint2*)(w + PART_OFF);
    k_tile_A<<<188 * 48, 256, 0, stream>>>(embed, Aw);
    k_tile_B<<<4 * 48, 512, 0, stream>>>(centers, Bw);
    k_chalf<<<1024, 256, 0, stream>>>(centers, ch);
    k_gemm<<<376, 1024, 0, stream>>>(Aw, Bw, ch, partb);
    k_merge<<<94, 256, 0, stream>>>(partb, out);
  } else {
    k_naive<<<6000, 256, 0, stream>>>(embed, centers, out);
  }
}